// Round 7
// baseline (134.903 us; speedup 1.0000x reference)
//
#include <hip/hip_runtime.h>

#define HH 160
#define WW 160
#define DD 160
#define BB 4
#define NPB (HH * WW * DD / 4)   // 1,024,000 float4 per batch
#define K1B 256                   // min-pass blocks per batch
#define MINB (K1B * BB)           // 1024 min blocks at the front of K1's grid
#define NTZ 10                    // z tiles (16 z each)
#define NTX 20                    // x tiles (8 x each)
#define NTY 20                    // y tiles (8 y each)
#define NTILES (BB * NTY * NTX * NTZ)   // 16000

typedef float vfloat4 __attribute__((ext_vector_type(4)));

// order-preserving float<->uint encode for unsigned atomicMin (verified round 5)
__device__ __forceinline__ unsigned enc_f32(float f) {
    unsigned u = __float_as_uint(f);
    return u ^ ((u & 0x80000000u) ? 0xFFFFFFFFu : 0x80000000u);
}
__device__ __forceinline__ float dec_f32(unsigned e) {
    return __uint_as_float(e ^ ((e & 0x80000000u) ? 0x80000000u : 0xFFFFFFFFu));
}

// fp64 affine constants from the 7 transfo params — formula verbatim from the
// verified rounds:  ix = R00*x + R01*y + R02*z + 79.5*(t0 - R00 - R01 - R02 + 1)
// Deterministic: K1 and K2 compute identical bits from identical inputs.
__device__ __forceinline__ void compute_cst(const float* __restrict__ transfos,
                                            int b, double* __restrict__ c) {
    const float* q = transfos + b * 7;
    double x = q[0], y = q[1], z = q[2], w = q[3];
    double tx = 2.0 * x, ty = 2.0 * y, tz = 2.0 * z;
    double twx = tx * w, twy = ty * w, twz = tz * w;
    double txx = tx * x, txy = ty * x, txz = tz * x;
    double tyy = ty * y, tyz = tz * y, tzz = tz * z;
    double R[3][3] = {
        {1.0 - (tyy + tzz), txy - twz,         txz + twy},
        {txy + twz,         1.0 - (txx + tzz), tyz - twx},
        {txz - twy,         tyz + twx,         1.0 - (txx + tyy)}
    };
    double t[3] = {(double)q[4], (double)q[5], (double)q[6]};
    #pragma unroll
    for (int r = 0; r < 3; r++) {
        c[r * 4 + 0] = R[r][0];
        c[r * 4 + 1] = R[r][1];
        c[r * 4 + 2] = R[r][2];
        c[r * 4 + 3] = 79.5 * (t[r] - R[r][0] - R[r][1] - R[r][2] + 1.0);
    }
}

// interval image of the tile's bounding box under the affine map (fp64).
// Same op order in K1 and K2 -> identical classification.
__device__ __forceinline__ void tile_bounds(const double* __restrict__ c,
                                            int xt, int yt, int zt,
                                            double* __restrict__ lo,
                                            double* __restrict__ hi) {
    const double X0 = (double)(xt * 8), X1 = X0 + 7.0;
    const double Y0 = (double)(yt * 8), Y1 = Y0 + 7.0;
    const double Z0 = (double)(zt * 16), Z1 = Z0 + 15.0;
    #pragma unroll
    for (int a = 0; a < 3; a++) {
        double l = c[a * 4 + 3], h = c[a * 4 + 3], t;
        t = c[a * 4 + 0]; if (t >= 0.0) { l += t * X0; h += t * X1; } else { l += t * X1; h += t * X0; }
        t = c[a * 4 + 1]; if (t >= 0.0) { l += t * Y0; h += t * Y1; } else { l += t * Y1; h += t * Y0; }
        t = c[a * 4 + 2]; if (t >= 0.0) { l += t * Z0; h += t * Z1; } else { l += t * Z1; h += t * Z0; }
        lo[a] = l; hi[a] = h;
    }
}

// ---- kernel 1: per-batch min (blocks [0,1024)) + survivor-tile gather ----
// Min-blocks stream 64 KB each -> block min -> encoded atomicMin(fillEnc[b]).
// Tile-blocks: thread 0 computes cst+interval into LDS; non-survivors exit;
// survivors run the verified round-6 gather (z-paired 8B loads), storing
// VALID lanes only (no fill dependency -> overlaps with the min pass).
__global__ __launch_bounds__(256) void min_gather_kernel(const float* __restrict__ img,
                                                         const float* __restrict__ transfos,
                                                         unsigned* __restrict__ fillEnc,
                                                         float* __restrict__ out) {
    const int tid = threadIdx.x;
    const int bid = blockIdx.x;

    __shared__ double sc[12];
    __shared__ int smaybe;
    __shared__ float sred[4];

    if (bid < MINB) {
        const float4* img4 = (const float4*)img;
        const int b = bid >> 8;
        const size_t base = (size_t)b * NPB;
        const int t0 = (bid & 255) * 256 + tid;   // < 65536
        const int S = K1B * 256;                   // 65536
        float m = 3.4e38f;
        #pragma unroll
        for (int r = 0; r < 4; r++) {
            const int i0 = t0 + 4 * r * S;
            float4 v0 = img4[base + i0];
            float4 v1 = img4[base + i0 + S];
            float4 v2 = img4[base + i0 + 2 * S];
            float4 v3 = make_float4(3.4e38f, 3.4e38f, 3.4e38f, 3.4e38f);
            if (i0 + 3 * S < NPB) v3 = img4[base + i0 + 3 * S];   // only r==3 can fail
            m = fminf(m, fminf(fminf(v0.x, v0.y), fminf(v0.z, v0.w)));
            m = fminf(m, fminf(fminf(v1.x, v1.y), fminf(v1.z, v1.w)));
            m = fminf(m, fminf(fminf(v2.x, v2.y), fminf(v2.z, v2.w)));
            m = fminf(m, fminf(fminf(v3.x, v3.y), fminf(v3.z, v3.w)));
        }
        #pragma unroll
        for (int o = 32; o >= 1; o >>= 1) m = fminf(m, __shfl_down(m, o));
        if ((tid & 63) == 0) sred[tid >> 6] = m;
        __syncthreads();
        if (tid == 0)
            atomicMin(&fillEnc[b], enc_f32(fminf(fminf(sred[0], sred[1]),
                                                 fminf(sred[2], sred[3]))));
        return;
    }

    int tt = bid - MINB;
    const int zt = tt % NTZ; tt /= NTZ;
    const int xt = tt % NTX; tt /= NTX;
    const int yt = tt % NTY;
    const int b = tt / NTY;

    if (tid == 0) {
        double c[12];
        compute_cst(transfos, b, c);
        double lo[3], hi[3];
        tile_bounds(c, xt, yt, zt, lo, hi);
        smaybe = (hi[0] >= -1e-3 && lo[0] <= 159.001 &&
                  hi[1] >= -1e-3 && lo[1] <= 159.001 &&
                  hi[2] >= -1e-3 && lo[2] <= 159.001);
        #pragma unroll
        for (int j = 0; j < 12; j++) sc[j] = c[j];
    }
    __syncthreads();
    if (!smaybe) return;   // all-invalid tile: K2 writes its fill

    // ---- survivor gather (verified round-6 math, valid-only stores) ----
    const int tz = tid & 3;
    const int tx = (tid >> 2) & 7;
    const int ty = tid >> 5;
    const int x = xt * 8 + tx;
    const int y = yt * 8 + ty;
    const int zq = zt * 16 + tz * 4;

    const double c0 = sc[0], c1 = sc[1], c2 = sc[2], c3 = sc[3];
    const double c4 = sc[4], c5 = sc[5], c6 = sc[6], c7 = sc[7];
    const double c8 = sc[8], c9 = sc[9], c10 = sc[10], c11 = sc[11];

    const double dx = (double)x, dy = (double)y, dz = (double)zq;
    double ixd = fma(c0, dx, fma(c1, dy, fma(c2, dz, c3)));
    double iyd = fma(c4, dx, fma(c5, dy, fma(c6, dz, c7)));
    double izd = fma(c8, dx, fma(c9, dy, fma(c10, dz, c11)));

    // exact per-k validity prescan (identical values to the main loop)
    bool anyv = false;
    {
        double ax = ixd, ay = iyd, az = izd;
        #pragma unroll
        for (int k = 0; k < 4; k++) {
            anyv = anyv || ((ax >= 0.0) && (ax <= 159.0) && (ay >= 0.0) &&
                            (ay <= 159.0) && (az >= 0.0) && (az <= 159.0));
            ax += c2; ay += c6; az += c10;
        }
    }
    if (!__any(anyv)) return;

    const float* base = img + (size_t)b * (HH * WW * DD);
    vfloat4 r;
    unsigned mask = 0;
    #pragma unroll
    for (int k = 0; k < 4; k++) {
        const bool valid = (ixd >= 0.0) && (ixd <= 159.0) && (iyd >= 0.0) &&
                           (iyd <= 159.0) && (izd >= 0.0) && (izd <= 159.0);
        if (valid) mask |= (1u << k);
        double flx = floor(ixd), fly = floor(iyd), flz = floor(izd);
        int x0 = (int)flx, y0 = (int)fly, z0 = (int)flz;
        x0 = min(max(x0, 0), 159);
        y0 = min(max(y0, 0), 159);
        z0 = min(max(z0, 0), 159);
        float fx = (float)(ixd - flx), fy = (float)(iyd - fly), fz = (float)(izd - flz);
        int x1 = min(x0 + 1, 159), y1 = min(y0 + 1, 159);
        const int zb = min(z0, 158);
        const bool ztop = (z0 == 159);
        const float* p00 = base + (y0 * WW + x0) * DD + zb;  // (y0, x0)
        const float* p10 = base + (y1 * WW + x0) * DD + zb;  // (y1, x0)
        const float* p01 = base + (y0 * WW + x1) * DD + zb;  // (y0, x1)
        const float* p11 = base + (y1 * WW + x1) * DD + zb;  // (y1, x1)
        float2 q00, q10, q01, q11;
        __builtin_memcpy(&q00, p00, 8);
        __builtin_memcpy(&q10, p10, 8);
        __builtin_memcpy(&q01, p01, 8);
        __builtin_memcpy(&q11, p11, 8);
        float v000 = ztop ? q00.y : q00.x, v001 = q00.y;
        float v010 = ztop ? q10.y : q10.x, v011 = q10.y;
        float v100 = ztop ? q01.y : q01.x, v101 = q01.y;
        float v110 = ztop ? q11.y : q11.x, v111 = q11.y;
        float wx0 = 1.0f - fx, wx1 = fx;
        float wy0 = 1.0f - fy, wy1 = fy;
        float wz0 = 1.0f - fz, wz1 = fz;
        // accumulate in the reference's (ox, oy, oz) loop order
        float acc;
        acc  = ((wx0 * wy0) * wz0) * v000;
        acc += ((wx0 * wy0) * wz1) * v001;
        acc += ((wx0 * wy1) * wz0) * v010;
        acc += ((wx0 * wy1) * wz1) * v011;
        acc += ((wx1 * wy0) * wz0) * v100;
        acc += ((wx1 * wy0) * wz1) * v101;
        acc += ((wx1 * wy1) * wz0) * v110;
        acc += ((wx1 * wy1) * wz1) * v111;
        r[k] = acc;
        ixd += c2; iyd += c6; izd += c10;
    }

    float* op = out + (size_t)((b * HH + y) * WW + x) * DD + zq;
    if (mask == 15u) {
        __builtin_nontemporal_store(r, (vfloat4*)op);
    } else {
        if (mask & 1u) __builtin_nontemporal_store(r[0], op);
        if (mask & 2u) __builtin_nontemporal_store(r[1], op + 1);
        if (mask & 4u) __builtin_nontemporal_store(r[2], op + 2);
        if (mask & 8u) __builtin_nontemporal_store(r[3], op + 3);
    }
}

// ---- kernel 2: fill all INVALID voxels (complement of K1's stores) ----
// Definitely-invalid tiles: full fill store. Definitely-fully-valid tiles
// (margin-safe interval: lo>=1e-3, hi<=158.999 per axis; per-voxel fp error
// << 1e-3): nothing to do. Boundary tiles: recompute per-k validity with
// code bit-identical to K1 and fill only the invalid elements.
__global__ __launch_bounds__(256) void fill_inv_kernel(const float* __restrict__ transfos,
                                                       const unsigned* __restrict__ fillEnc,
                                                       float* __restrict__ out) {
    const int bzc = blockIdx.z;
    const int b = bzc / NTY;
    const int yt = bzc - b * NTY;
    const int xt = blockIdx.y;
    const int zt = blockIdx.x;
    const int tid = threadIdx.x;

    __shared__ double sc[12];
    __shared__ int scls;   // 0 = all-invalid, 1 = boundary, 2 = fully-valid
    if (tid == 0) {
        double c[12];
        compute_cst(transfos, b, c);
        double lo[3], hi[3];
        tile_bounds(c, xt, yt, zt, lo, hi);
        const bool maybe = (hi[0] >= -1e-3 && lo[0] <= 159.001 &&
                            hi[1] >= -1e-3 && lo[1] <= 159.001 &&
                            hi[2] >= -1e-3 && lo[2] <= 159.001);
        const bool fully = (lo[0] >= 1e-3 && hi[0] <= 158.999 &&
                            lo[1] >= 1e-3 && hi[1] <= 158.999 &&
                            lo[2] >= 1e-3 && hi[2] <= 158.999);
        scls = maybe ? (fully ? 2 : 1) : 0;
        #pragma unroll
        for (int j = 0; j < 12; j++) sc[j] = c[j];
    }
    __syncthreads();
    const int cls = scls;
    if (cls == 2) return;                       // K1 stored every voxel

    const int tz = tid & 3;
    const int tx = (tid >> 2) & 7;
    const int ty = tid >> 5;
    const int x = xt * 8 + tx;
    const int y = yt * 8 + ty;
    const int zq = zt * 16 + tz * 4;
    float* op = out + (size_t)((b * HH + y) * WW + x) * DD + zq;
    const float fillv = dec_f32(fillEnc[b]);

    if (cls == 0) {                             // K1 stored nothing
        vfloat4 v; v[0] = fillv; v[1] = fillv; v[2] = fillv; v[3] = fillv;
        __builtin_nontemporal_store(v, (vfloat4*)op);
        return;
    }

    // boundary tile: per-voxel validity, bit-identical to K1's sequence
    const double c0 = sc[0], c1 = sc[1], c2 = sc[2], c3 = sc[3];
    const double c4 = sc[4], c5 = sc[5], c6 = sc[6], c7 = sc[7];
    const double c8 = sc[8], c9 = sc[9], c10 = sc[10], c11 = sc[11];
    const double dx = (double)x, dy = (double)y, dz = (double)zq;
    double ixd = fma(c0, dx, fma(c1, dy, fma(c2, dz, c3)));
    double iyd = fma(c4, dx, fma(c5, dy, fma(c6, dz, c7)));
    double izd = fma(c8, dx, fma(c9, dy, fma(c10, dz, c11)));
    unsigned mask = 0;
    #pragma unroll
    for (int k = 0; k < 4; k++) {
        const bool valid = (ixd >= 0.0) && (ixd <= 159.0) && (iyd >= 0.0) &&
                           (iyd <= 159.0) && (izd >= 0.0) && (izd <= 159.0);
        if (valid) mask |= (1u << k);
        ixd += c2; iyd += c6; izd += c10;
    }
    if (mask == 15u) return;
    if (mask == 0u) {
        vfloat4 v; v[0] = fillv; v[1] = fillv; v[2] = fillv; v[3] = fillv;
        __builtin_nontemporal_store(v, (vfloat4*)op);
        return;
    }
    if (!(mask & 1u)) __builtin_nontemporal_store(fillv, op);
    if (!(mask & 2u)) __builtin_nontemporal_store(fillv, op + 1);
    if (!(mask & 4u)) __builtin_nontemporal_store(fillv, op + 2);
    if (!(mask & 8u)) __builtin_nontemporal_store(fillv, op + 3);
}

extern "C" void kernel_launch(void* const* d_in, const int* in_sizes, int n_in,
                              void* d_out, int out_size, void* d_ws, size_t ws_size,
                              hipStream_t stream) {
    const float* img = (const float*)d_in[0];
    const float* transfos = (const float*)d_in[1];
    float* out = (float*)d_out;
    unsigned* fillEnc = (unsigned*)d_ws;        // 16 B (only workspace use)

    hipMemsetAsync(d_ws, 0xFF, 16, stream);     // fillEnc = +inf keys (verified R5)
    min_gather_kernel<<<dim3(MINB + NTILES), 256, 0, stream>>>(img, transfos,
                                                               fillEnc, out);
    fill_inv_kernel<<<dim3(NTZ, NTX, NTY * BB), 256, 0, stream>>>(transfos,
                                                                  fillEnc, out);
}